// Round 26
// baseline (11.071 us; speedup 1.0000x reference)
//
#include <hip/hip_runtime.h>

// PSRoIPool (R-FCN), VERIFIED semantics (r23 pass; r25 10.06 µs):
// features [4,490,38,38] f32, rois [256,5] f32, out [256,10,7,7] f32.
// CRITICAL numerics (do not touch — r1-r22 forensics):
//  - bin = roi * fl32(1/7)  (reciprocal multiply, NOT division)
//  - boundary = fl32(fl32(p*bin) + start): two roundings, fma blocked.
// r26: latency-bound at 1.9 waves/SIMD (665K scattered loads ~ 1.2 µs of L2
// transactions, yet 10 µs wall). Fix TLP: 8 threads per output (one per
// window row, max height 7), 3-step width-8 shuffle reduce -> 61 waves/CU.
// Sum order changes (row-tree) — only the window SUM, not the boundary
// floor/ceil decisions; f32 reorder noise ~1e-6 rel << 0.0725 threshold.

#pragma clang fp contract(off)

#define PS 7
#define DD 10
#define CC 490
#define HH 38
#define WW 38

__device__ __forceinline__ float mul_add_strict_f32(float a, float b, float c) {
#pragma clang fp contract(off)
    float p = a * b;
    asm volatile("" : "+v"(p));   // block fma contraction
    return p + c;
}

__global__ __launch_bounds__(256) void psroi_pool_kernel(
    const float* __restrict__ feat,
    const float* __restrict__ rois,
    float* __restrict__ out,
    int total)
{
#pragma clang fp contract(off)
    int gid  = blockIdx.x * blockDim.x + threadIdx.x;
    int idx  = gid >> 3;          // output element
    int lane = gid & 7;           // window row handled by this thread
    if (idx >= total) return;

    int pw = idx % PS;
    int ph = (idx / PS) % PS;
    int d  = (idx / (PS * PS)) % DD;
    int r  = idx / (PS * PS * DD);

    const float* roi = rois + (size_t)r * 5;
    int b = (int)roi[0];

    float xs = rintf(roi[1]) * 0.0625f;
    float ys = rintf(roi[2]) * 0.0625f;
    float xe = rintf(roi[3] + 1.0f) * 0.0625f;
    float ye = rintf(roi[4] + 1.0f) * 0.0625f;

    float roi_w = fmaxf(xe - xs, 0.1f);
    float roi_h = fmaxf(ye - ys, 0.1f);

    // RECIPROCAL MULTIPLY (verified): bin = roi * fl32(1/7)
    const float RECIP7 = 1.0f / 7.0f;
    float bin_w = roi_w * RECIP7;
    float bin_h = roi_h * RECIP7;

    float hs_f = floorf(mul_add_strict_f32((float)ph,       bin_h, ys));
    float he_f = ceilf (mul_add_strict_f32((float)(ph + 1), bin_h, ys));
    float ws_f = floorf(mul_add_strict_f32((float)pw,       bin_w, xs));
    float we_f = ceilf (mul_add_strict_f32((float)(pw + 1), bin_w, xs));

    int hstart = (int)fminf(fmaxf(hs_f, 0.0f), (float)HH);
    int hend   = (int)fminf(fmaxf(he_f, 0.0f), (float)HH);
    int wstart = (int)fminf(fmaxf(ws_f, 0.0f), (float)WW);
    int wend   = (int)fminf(fmaxf(we_f, 0.0f), (float)WW);

    int c = (d * PS + ph) * PS + pw;
    const float* fp = feat + ((size_t)b * CC + c) * (HH * WW);

    // This thread's window row (max window height 7 <= 8 lanes).
    float partial = 0.0f;
    int h = hstart + lane;
    if (h < hend) {
        const float* row = fp + h * WW;
        for (int w = wstart; w < wend; ++w) {
            partial += row[w];
        }
    }

    // 8-lane tree reduction (within-wave; width 8 divides 64).
    partial += __shfl_xor(partial, 1, 8);
    partial += __shfl_xor(partial, 2, 8);
    partial += __shfl_xor(partial, 4, 8);

    if (lane == 0) {
        int cnt = (hend - hstart) * (wend - wstart);
        out[idx] = (cnt > 0) ? (partial / (float)cnt) : 0.0f;
    }
}

extern "C" void kernel_launch(void* const* d_in, const int* in_sizes, int n_in,
                              void* d_out, int out_size, void* d_ws, size_t ws_size,
                              hipStream_t stream) {
    const float* feat = (const float*)d_in[0];
    const float* rois = (const float*)d_in[1];
    float* out = (float*)d_out;

    int total = out_size;                 // 125440
    long long threads = (long long)total * 8;   // 8 lanes per output
    int block = 256;
    int grid = (int)((threads + block - 1) / block);
    psroi_pool_kernel<<<grid, block, 0, stream>>>(feat, rois, out, total);
}

// Round 27
// 9.984 us; speedup vs baseline: 1.1089x; 1.1089x over previous
//
#include <hip/hip_runtime.h>

// PSRoIPool (R-FCN) — FINAL (r25 structure, best measured: 10.06 µs).
// features [4,490,38,38] f32, rois [256,5] f32, out [256,10,7,7] f32.
// CRITICAL numerics (verified by r1-r23 forensics — do not touch):
//  - bin = roi * fl32(1/7)  (reciprocal multiply, NOT division): matches the
//    reference's strength-reduced division; flips exact-integer end
//    boundaries (7|16*roi set) to N+eps -> ceil N+1.
//  - boundary = fl32(fl32(p*bin) + start): two roundings, fma blocked by an
//    asm opacity barrier; fp contract off.
// Perf ledger: r23 serial 11.0 | r24 unconditional-clamp unroll 30.1 (8x L2
// transactions) | r25 predicated burst 10.06 | r26 8-lane row-split 11.07
// (TLP is not the limiter). Kernel-proper work ~1-2 µs; wall is dominated by
// a fixed ~9 µs floor. Zero inter-output reuse exists (each output reads a
// unique (b, c=(d*7+ph)*7+pw) plane), so traffic is already minimal.

#pragma clang fp contract(off)

#define PS 7
#define DD 10
#define CC 490
#define HH 38
#define WW 38

__device__ __forceinline__ float mul_add_strict_f32(float a, float b, float c) {
#pragma clang fp contract(off)
    float p = a * b;
    asm volatile("" : "+v"(p));   // block fma contraction
    return p + c;
}

__global__ __launch_bounds__(256) void psroi_pool_kernel(
    const float* __restrict__ feat,
    const float* __restrict__ rois,
    float* __restrict__ out,
    int total)
{
#pragma clang fp contract(off)
    int idx = blockIdx.x * blockDim.x + threadIdx.x;
    if (idx >= total) return;

    int pw = idx % PS;
    int ph = (idx / PS) % PS;
    int d  = (idx / (PS * PS)) % DD;
    int r  = idx / (PS * PS * DD);

    const float* roi = rois + (size_t)r * 5;
    int b = (int)roi[0];

    float xs = rintf(roi[1]) * 0.0625f;
    float ys = rintf(roi[2]) * 0.0625f;
    float xe = rintf(roi[3] + 1.0f) * 0.0625f;
    float ye = rintf(roi[4] + 1.0f) * 0.0625f;

    float roi_w = fmaxf(xe - xs, 0.1f);
    float roi_h = fmaxf(ye - ys, 0.1f);

    // RECIPROCAL MULTIPLY (verified): bin = roi * fl32(1/7)
    const float RECIP7 = 1.0f / 7.0f;
    float bin_w = roi_w * RECIP7;
    float bin_h = roi_h * RECIP7;

    float hs_f = floorf(mul_add_strict_f32((float)ph,       bin_h, ys));
    float he_f = ceilf (mul_add_strict_f32((float)(ph + 1), bin_h, ys));
    float ws_f = floorf(mul_add_strict_f32((float)pw,       bin_w, xs));
    float we_f = ceilf (mul_add_strict_f32((float)(pw + 1), bin_w, xs));

    int hstart = (int)fminf(fmaxf(hs_f, 0.0f), (float)HH);
    int hend   = (int)fminf(fmaxf(he_f, 0.0f), (float)HH);
    int wstart = (int)fminf(fmaxf(ws_f, 0.0f), (float)WW);
    int wend   = (int)fminf(fmaxf(we_f, 0.0f), (float)WW);

    int c = (d * PS + ph) * PS + pw;
    const float* fp = feat + ((size_t)b * CC + c) * (HH * WW);

    // Fully unrolled, PREDICATED window sum (exec-masked loads: only
    // in-window lanes issue L2 transactions; per-row loads issue as an
    // independent burst, adds after). Ascending (h,w) masked +0.0f adds keep
    // the sum bit-compatible with the verified r23 result.
    float sum = 0.0f;
#pragma unroll
    for (int hh = 0; hh < 7; ++hh) {
        int h = hstart + hh;
        bool vh = (h < hend);
        const float* row = fp + h * WW;
        float v[7];
#pragma unroll
        for (int ww = 0; ww < 7; ++ww) {
            int w = wstart + ww;
            v[ww] = (vh && w < wend) ? row[w] : 0.0f;
        }
#pragma unroll
        for (int ww = 0; ww < 7; ++ww) {
            sum += v[ww];
        }
    }

    int cnt = (hend - hstart) * (wend - wstart);
    out[idx] = (cnt > 0) ? (sum / (float)cnt) : 0.0f;
}

extern "C" void kernel_launch(void* const* d_in, const int* in_sizes, int n_in,
                              void* d_out, int out_size, void* d_ws, size_t ws_size,
                              hipStream_t stream) {
    const float* feat = (const float*)d_in[0];
    const float* rois = (const float*)d_in[1];
    float* out = (float*)d_out;

    int total = out_size;  // 125440
    int block = 256;
    int grid = (total + block - 1) / block;
    psroi_pool_kernel<<<grid, block, 0, stream>>>(feat, rois, out, total);
}